// Round 3
// baseline (285.251 us; speedup 1.0000x reference)
//
#include <hip/hip_runtime.h>

// out[b,m,f,t] = sum_c W[m,f,c] * x[b,m,c,t]
// x: [B=256][NM=5][NC=64][T=1024] f32, W: [NM=5][NF=40][NC=64] f32
// out: [B][NM][NF=40][T] f32
//
// Memory-bound: 545 MB @ ~7.0 TB/s measured ceiling => ~80-86 us floor.
// R2: eliminate the 2.5-rounds-in-3 dispatch tail. 5120 quarter-row tiles,
// persistent grid of 1024 blocks x exactly 5 tiles each (perfect balance).
// 1 float/thread -> 40 accumulator VGPRs, dense 256B/wave loads+stores.

#define B_  256
#define NM_ 5
#define NC_ 64
#define T_  1024
#define NF_ 40
#define QT_ 256                       // t's per tile
#define NTILES (B_ * NM_ * (T_/QT_)) // 5120
#define GRID_ 1024
#define PER_BLOCK (NTILES / GRID_)   // 5, exact
#define CCHUNK 8

__global__ __launch_bounds__(256, 4) void trca_einsum_kernel(
    const float* __restrict__ x,
    const float* __restrict__ W,
    float* __restrict__ out)
{
#pragma unroll 1
    for (int k = 0; k < PER_BLOCK; ++k) {
        const int tile = blockIdx.x + k * GRID_;
        const int q    = tile & 3;          // quarter index within T
        const int bm   = tile >> 2;         // b*NM + m
        const int m    = bm % NM_;
        const int t0   = q * QT_ + threadIdx.x;

        const float* __restrict__ xp = x + (size_t)bm * NC_ * T_ + t0;  // stride T_ per c
        const float* __restrict__ wp = W + (size_t)m * NF_ * NC_;       // W[m,f,c]
        float* __restrict__ op = out + (size_t)bm * NF_ * T_ + t0;      // stride T_ per f

        float acc[NF_];
#pragma unroll
        for (int f = 0; f < NF_; ++f) acc[f] = 0.0f;

#pragma unroll 1
        for (int cc = 0; cc < NC_; cc += CCHUNK) {
            float xv[CCHUNK];
#pragma unroll
            for (int i = 0; i < CCHUNK; ++i) {
                xv[i] = xp[(size_t)(cc + i) * T_];
            }
#pragma unroll
            for (int i = 0; i < CCHUNK; ++i) {
#pragma unroll
                for (int f = 0; f < NF_; ++f) {
                    acc[f] += wp[f * NC_ + cc + i] * xv[i];  // w: wave-uniform s_load
                }
            }
        }

#pragma unroll
        for (int f = 0; f < NF_; ++f) {
            op[(size_t)f * T_] = acc[f];
        }
    }
}

extern "C" void kernel_launch(void* const* d_in, const int* in_sizes, int n_in,
                              void* d_out, int out_size, void* d_ws, size_t ws_size,
                              hipStream_t stream)
{
    const float* x = (const float*)d_in[0];
    const float* W = (const float*)d_in[1];
    float* out = (float*)d_out;

    trca_einsum_kernel<<<GRID_, 256, 0, stream>>>(x, W, out);
}

// Round 4
// 123.589 us; speedup vs baseline: 2.3081x; 2.3081x over previous
//
#include <hip/hip_runtime.h>

// out[b,m,f,t] = sum_c W[m,f,c] * x[b,m,c,t]
// x: [B=256][NM=5][NC=64][T=1024] f32, W: [NM=5][NF=40][NC=64] f32
// out: [B][NM][NF=40][T] f32
//
// Memory-bound: 545 MB @ ~6.3-7.0 TB/s => ~80-86 us floor.
// R3: R1 tiling (proven codegen: acc stays in VGPRs) + explicit register
// double-buffer on the c-chunks so each wave ALWAYS has a load batch in
// flight (R1 was ~50% load duty -> 4.5 TB/s effective; this targets ~100%).

#define B_  256
#define NM_ 5
#define NC_ 64
#define T_  1024
#define NF_ 40
#define CCHUNK 4

__global__ __launch_bounds__(256, 4) void trca_einsum_kernel(
    const float* __restrict__ x,
    const float* __restrict__ W,
    float* __restrict__ out)
{
    // grid.x = B*NM*2 ; low bit = t-half
    const int tile = blockIdx.x & 1;
    const int bm   = blockIdx.x >> 1;          // b*NM + m
    const int m    = bm % NM_;
    const int t0   = tile * (T_ / 2) + threadIdx.x * 2;

    const float* __restrict__ xp = x + (size_t)bm * NC_ * T_ + t0;   // stride T_ per c
    const float* __restrict__ wp = W + (size_t)m * NF_ * NC_;        // W[m,f,c]
    float* __restrict__ op = out + (size_t)bm * NF_ * T_ + t0;       // stride T_ per f

    float acc0[NF_], acc1[NF_];
#pragma unroll
    for (int f = 0; f < NF_; ++f) { acc0[f] = 0.0f; acc1[f] = 0.0f; }

    float2 bufA[CCHUNK], bufB[CCHUNK];

    // Prologue: chunk 0 -> bufA.
#pragma unroll
    for (int i = 0; i < CCHUNK; ++i)
        bufA[i] = *reinterpret_cast<const float2*>(xp + (size_t)i * T_);

    // Main: pairs of chunks. Iter at cc computes chunks (cc, cc+4),
    // prefetches (cc+4, cc+8). Loads always outstanding during FMAs.
#pragma unroll 1
    for (int cc = 0; cc < NC_ - 2 * CCHUNK; cc += 2 * CCHUNK) {
        // prefetch chunk cc+4 -> bufB
#pragma unroll
        for (int i = 0; i < CCHUNK; ++i)
            bufB[i] = *reinterpret_cast<const float2*>(xp + (size_t)(cc + CCHUNK + i) * T_);
        // compute chunk cc from bufA
#pragma unroll
        for (int i = 0; i < CCHUNK; ++i) {
#pragma unroll
            for (int f = 0; f < NF_; ++f) {
                const float w = wp[f * NC_ + cc + i];
                acc0[f] += w * bufA[i].x;
                acc1[f] += w * bufA[i].y;
            }
        }
        // prefetch chunk cc+8 -> bufA
#pragma unroll
        for (int i = 0; i < CCHUNK; ++i)
            bufA[i] = *reinterpret_cast<const float2*>(xp + (size_t)(cc + 2 * CCHUNK + i) * T_);
        // compute chunk cc+4 from bufB
#pragma unroll
        for (int i = 0; i < CCHUNK; ++i) {
#pragma unroll
            for (int f = 0; f < NF_; ++f) {
                const float w = wp[f * NC_ + cc + CCHUNK + i];
                acc0[f] += w * bufB[i].x;
                acc1[f] += w * bufB[i].y;
            }
        }
    }

    // Epilogue: A holds chunk 56..59; prefetch 60..63, compute both.
    {
        const int cc = NC_ - 2 * CCHUNK;  // 56
#pragma unroll
        for (int i = 0; i < CCHUNK; ++i)
            bufB[i] = *reinterpret_cast<const float2*>(xp + (size_t)(cc + CCHUNK + i) * T_);
#pragma unroll
        for (int i = 0; i < CCHUNK; ++i) {
#pragma unroll
            for (int f = 0; f < NF_; ++f) {
                const float w = wp[f * NC_ + cc + i];
                acc0[f] += w * bufA[i].x;
                acc1[f] += w * bufA[i].y;
            }
        }
#pragma unroll
        for (int i = 0; i < CCHUNK; ++i) {
#pragma unroll
            for (int f = 0; f < NF_; ++f) {
                const float w = wp[f * NC_ + cc + CCHUNK + i];
                acc0[f] += w * bufB[i].x;
                acc1[f] += w * bufB[i].y;
            }
        }
    }

#pragma unroll
    for (int f = 0; f < NF_; ++f) {
        __builtin_nontemporal_store(acc0[f], op + (size_t)f * T_);
        __builtin_nontemporal_store(acc1[f], op + (size_t)f * T_ + 1);
    }
}

extern "C" void kernel_launch(void* const* d_in, const int* in_sizes, int n_in,
                              void* d_out, int out_size, void* d_ws, size_t ws_size,
                              hipStream_t stream)
{
    const float* x = (const float*)d_in[0];
    const float* W = (const float*)d_in[1];
    float* out = (float*)d_out;

    const int grid = B_ * NM_ * 2;   // 2560 blocks
    trca_einsum_kernel<<<grid, 256, 0, stream>>>(x, W, out);
}